// Round 2
// baseline (1103.418 us; speedup 1.0000x reference)
//
#include <hip/hip_runtime.h>
#include <cstdint>

#define VOCAB 500000
#define STEPS 64
#define EPSF 1e-8f

__device__ __forceinline__ float sigm(float x) { return 1.f / (1.f + expf(-x)); }
__device__ __forceinline__ float dot4(float4 a, float4 b) {
    return a.x * b.x + a.y * b.y + a.z * b.z + a.w * b.w;
}
__device__ __forceinline__ unsigned long long ullmax(unsigned long long a, unsigned long long b) {
    return a > b ? a : b;
}
// order-preserving float->uint32 map (monotone increasing)
__device__ __forceinline__ unsigned fmap(float f) {
    unsigned u = __float_as_uint(f);
    return (u & 0x80000000u) ? ~u : (u | 0x80000000u);
}

// Pin a float4's lanes into VGPRs: makes the value opaque to the compiler so it
// CANNOT be rematerialized by re-loading from memory inside the step loop.
#define PIN4(v) asm volatile("" : "+v"(v.x), "+v"(v.y), "+v"(v.z), "+v"(v.w))

// ---------------- Kernel A: 64-step LSTM recurrence (single block, 512 threads) ----------------
// Thread r owns gate-row r. __launch_bounds__(512, 2): min 2 waves/EU -> 256-VGPR budget.
// R1 evidence: previous build allocated only 128 VGPRs (attribute ignored) -> weights
// re-read from L2 every step -> 6.06 us/step. PIN4 forces the 192 weight VGPRs resident.
//   wa[32] float4 = w_ih[r][0:128]   (multiplies x=c)   128 VGPR
//   wu[16] float4 = w_hh[r][0:64]    (U head)            64 VGPR
//   U tail (cols 64..127): LDS, 128 KB, swizzled.
__global__ void __launch_bounds__(512, 2) __attribute__((amdgpu_waves_per_eu(2, 2)))
lstm_kernel(
    const float* __restrict__ inp, const float* __restrict__ embed,
    const float* __restrict__ w_ih, const float* __restrict__ w_hh,
    const float* __restrict__ b_ih, const float* __restrict__ b_hh,
    float* __restrict__ out_cs,                 // d_out[0 .. 64*128)
    unsigned long long* __restrict__ slots)     // ws: 64 argmax slots
{
    __shared__ float4 whh_tail[512 * 16];   // 128 KB: w_hh[r][64:128], swizzled [r][j4 ^ (r&15)]
    __shared__ float vv[256];               // [x(128) ; h(128)]
    __shared__ float gates[512];
    const int r = threadIdx.x;

    if (r < STEPS) slots[r] = 0ull;   // init argmax slots (vocab kernel is stream-ordered after)

    const float4* wihr = (const float4*)(w_ih + (size_t)r * 256);
    const float4* whhr = (const float4*)(w_hh + (size_t)r * 128);

    // kv = b_ih[r] + b_hh[r] + w_ih[r][128:256] . inp   (constant across steps) — streamed
    float kv = b_ih[r] + b_hh[r];
    {
        const float4* wib = wihr + 32;
        const float4* inp4 = (const float4*)inp;
        float k0 = 0.f, k1 = 0.f;
#pragma unroll 2
        for (int j = 0; j < 32; j += 2) {
            k0 += dot4(wib[j], inp4[j]);
            k1 += dot4(wib[j + 1], inp4[j + 1]);
        }
        kv += k0 + k1;
    }

    // stage w_hh[:, 64:128] into LDS (coalesced: consecutive threads hit consecutive float4s)
#pragma unroll 2
    for (int k = 0; k < 16; ++k) {
        int f = r + k * 512;
        int row = f >> 4, cj = f & 15;
        const float4* src = (const float4*)(w_hh + (size_t)row * 128);
        whh_tail[row * 16 + (cj ^ (row & 15))] = src[16 + cj];
    }

    // persistent register weights — loaded once, then PINNED so the step loop cannot
    // re-load them from memory (the R1 6us/step regression).
    float4 wa[32], wu[16];
#pragma unroll
    for (int j = 0; j < 32; ++j) wa[j] = wihr[j];
#pragma unroll
    for (int j = 0; j < 16; ++j) wu[j] = whhr[j];
#pragma unroll
    for (int j = 0; j < 32; ++j) PIN4(wa[j]);
#pragma unroll
    for (int j = 0; j < 16; ++j) PIN4(wu[j]);

    if (r < 128) { vv[r] = embed[r]; vv[128 + r] = 0.f; }  // x0 = embed[0], h0 = 0
    float creg = 0.f;
    __syncthreads();

    const int rsw = (r << 4);
    const int rm = r & 15;
    for (int t = 0; t < STEPS; ++t) {
        const float4* v4 = (const float4*)vv;
        float a0 = 0.f, a1 = 0.f;
#pragma unroll
        for (int j = 0; j < 32; j += 2) {       // A @ x
            a0 += dot4(wa[j], v4[j]);
            a1 += dot4(wa[j + 1], v4[j + 1]);
        }
#pragma unroll
        for (int j = 0; j < 16; j += 2) {       // U_head @ h[0:64]
            a0 += dot4(wu[j], v4[32 + j]);
            a1 += dot4(wu[j + 1], v4[32 + j + 1]);
        }
#pragma unroll 4
        for (int j4 = 0; j4 < 16; ++j4) {       // U_tail @ h[64:128] from LDS
            float4 w = whh_tail[rsw + (j4 ^ rm)];
            a0 += dot4(w, v4[48 + j4]);
        }
        gates[r] = kv + a0 + a1;
        __syncthreads();
        if (r < 128) {
            float ig = sigm(gates[r]);
            float fg = sigm(gates[128 + r]);
            float gg = tanhf(gates[256 + r]);
            float og = sigm(gates[384 + r]);
            float cn = fg * creg + ig * gg;
            float hn = og * tanhf(cn);
            creg = cn;
            vv[r] = cn;           // next x = c_new
            vv[128 + r] = hn;     // next h
            out_cs[t * 128 + r] = cn;
        }
        __syncthreads();
    }
}

// ---------------- Kernel B: one pass over embed, 64 dots/row + norm + argmax ----------------
// 256 threads, 256 rows/block (4 tiles of 64). Thread = (tx=tid&15 -> t in {tx,tx+16,tx+32,tx+48},
// ry=tid>>4 -> rows {ry,ry+16,ry+32,ry+48}). ssq computed at staging time (per-(row,j4) partials),
// inner loop is pure acc FMAs: 8 b128 LDS reads + 16 dot4 per j4.
__global__ __launch_bounds__(256)
__attribute__((amdgpu_waves_per_eu(2, 2)))
void vocab_kernel(
    const float* __restrict__ embed,
    const float* __restrict__ cs,               // d_out[0..8192): [64][128] c vectors
    unsigned long long* __restrict__ slots)
{
    __shared__ float4 c_lds[64 * 32];   // 32 KB, swizzled [t][j4 ^ (t&31)]
    __shared__ float4 e_lds[64 * 32];   // 32 KB, swizzled; reused as u64 reduction scratch
    __shared__ float ssq_part[64 * 32]; // 8 KB: per-(row,j4) |e4|^2 partials, written at staging

    const int tid = threadIdx.x;
    const int tx = tid & 15, ry = tid >> 4;

    // stage c matrix once (swizzled)
    const float4* cs4 = (const float4*)cs;
#pragma unroll 2
    for (int k = 0; k < 8; ++k) {
        int f = tid + k * 256;
        int row = f >> 5, j4 = f & 31;
        c_lds[row * 32 + (j4 ^ (row & 31))] = cs4[f];
    }

    unsigned long long running = 0ull;   // tid<64: best key for t = tid
    const long long blockbase = (long long)blockIdx.x * 256;
    const float4* embed4 = (const float4*)embed;

    int Pe[4], Pc[4];
#pragma unroll
    for (int rr = 0; rr < 4; ++rr) { int row = ry + 16 * rr; Pe[rr] = row * 32 + (row & 31); }
#pragma unroll
    for (int tt = 0; tt < 4; ++tt) { int t = tx + 16 * tt; Pc[tt] = t * 32 + (t & 31); }

    for (int tile = 0; tile < 4; ++tile) {
        const long long rowbase = blockbase + tile * 64;
        __syncthreads();   // prev reduction reads done before restaging e_lds / ssq_part
#pragma unroll 2
        for (int k = 0; k < 8; ++k) {
            int f = tid + k * 256;
            int row = f >> 5, j4 = f & 31;
            long long grow = rowbase + row;
            float4 val = make_float4(0.f, 0.f, 0.f, 0.f);
            if (grow < VOCAB) val = embed4[grow * 32 + j4];
            e_lds[row * 32 + (j4 ^ (row & 31))] = val;
            ssq_part[row * 32 + j4] = dot4(val, val);
        }
        __syncthreads();

        float acc[4][4];
#pragma unroll
        for (int rr = 0; rr < 4; ++rr)
#pragma unroll
            for (int tt = 0; tt < 4; ++tt) acc[rr][tt] = 0.f;

#pragma unroll 2
        for (int j4 = 0; j4 < 32; ++j4) {
            float4 c0 = c_lds[Pc[0] ^ j4];
            float4 c1 = c_lds[Pc[1] ^ j4];
            float4 c2 = c_lds[Pc[2] ^ j4];
            float4 c3 = c_lds[Pc[3] ^ j4];
#pragma unroll
            for (int rr = 0; rr < 4; ++rr) {
                float4 e = e_lds[Pe[rr] ^ j4];
                acc[rr][0] += dot4(e, c0);
                acc[rr][1] += dot4(e, c1);
                acc[rr][2] += dot4(e, c2);
                acc[rr][3] += dot4(e, c3);
            }
        }

        // per-row inv-norm from staged partials (broadcast reads, once per tile)
        float inv[4];
        long long grows[4];
#pragma unroll
        for (int rr = 0; rr < 4; ++rr) {
            int row = ry + 16 * rr;
            float s0 = 0.f, s1 = 0.f;
#pragma unroll 4
            for (int j = 0; j < 32; j += 2) {
                s0 += ssq_part[row * 32 + j];
                s1 += ssq_part[row * 32 + j + 1];
            }
            inv[rr] = 1.f / fmaxf(sqrtf(s0 + s1), EPSF);
            grows[rr] = rowbase + row;
        }
        __syncthreads();   // all e_lds reads done; safe to reuse as scratch

        unsigned long long* red = (unsigned long long*)e_lds;  // [tt*256 + tx*16 + ry]
#pragma unroll
        for (int tt = 0; tt < 4; ++tt) {
            unsigned long long k = 0ull;
#pragma unroll
            for (int rr = 0; rr < 4; ++rr) {
                if (grows[rr] < VOCAB) {
                    float q = acc[rr][tt] * inv[rr];
                    unsigned long long key = ((unsigned long long)fmap(q) << 32)
                                           | (unsigned)(0x7FFFFFFF - (int)grows[rr]);
                    k = ullmax(k, key);
                }
            }
            red[tt * 256 + tx * 16 + ry] = k;
        }
        __syncthreads();

        if (tid < 64) {
            int t = tid, ttx = t & 15, ttt = t >> 4;
#pragma unroll
            for (int r2 = 0; r2 < 16; ++r2)
                running = ullmax(running, red[ttt * 256 + ttx * 16 + r2]);
        }
    }

    if (tid < 64) atomicMax(&slots[tid], running);
}

// ---------------- Kernel C: decode argmax slots to float indices ----------------
__global__ void finalize_kernel(const unsigned long long* __restrict__ slots,
                                float* __restrict__ out_dec)
{
    int t = threadIdx.x;
    if (t < STEPS) {
        unsigned idx = 0x7FFFFFFFu - (unsigned)(slots[t] & 0xFFFFFFFFu);
        out_dec[t] = (float)idx;
    }
}

extern "C" void kernel_launch(void* const* d_in, const int* in_sizes, int n_in,
                              void* d_out, int out_size, void* d_ws, size_t ws_size,
                              hipStream_t stream) {
    (void)in_sizes; (void)n_in; (void)out_size; (void)ws_size;
    const float* inp   = (const float*)d_in[0];
    const float* embed = (const float*)d_in[1];
    const float* w_ih  = (const float*)d_in[2];
    const float* w_hh  = (const float*)d_in[3];
    const float* b_ih  = (const float*)d_in[4];
    const float* b_hh  = (const float*)d_in[5];
    float* out = (float*)d_out;
    unsigned long long* slots = (unsigned long long*)d_ws;

    hipLaunchKernelGGL(lstm_kernel, dim3(1), dim3(512), 0, stream,
                       inp, embed, w_ih, w_hh, b_ih, b_hh, out, slots);
    const int nblocks = (VOCAB + 255) / 256;   // 1954
    hipLaunchKernelGGL(vocab_kernel, dim3(nblocks), dim3(256), 0, stream,
                       embed, out, slots);
    hipLaunchKernelGGL(finalize_kernel, dim3(1), dim3(64), 0, stream,
                       slots, out + STEPS * 128);
}

// Round 3
// 834.435 us; speedup vs baseline: 1.3224x; 1.3224x over previous
//
#include <hip/hip_runtime.h>
#include <cstdint>

#define VOCAB 500000
#define STEPS 64
#define EPSF 1e-8f

__device__ __forceinline__ float sigm(float x) { return 1.f / (1.f + expf(-x)); }
__device__ __forceinline__ float dot4(float4 a, float4 b) {
    return a.x * b.x + a.y * b.y + a.z * b.z + a.w * b.w;
}
__device__ __forceinline__ unsigned long long ullmax(unsigned long long a, unsigned long long b) {
    return a > b ? a : b;
}
// order-preserving float->uint32 map (monotone increasing)
__device__ __forceinline__ unsigned fmap(float f) {
    unsigned u = __float_as_uint(f);
    return (u & 0x80000000u) ? ~u : (u | 0x80000000u);
}

// ---------------- Kernel A: 64-step LSTM recurrence (single block, 1024 threads) ----------------
// R1/R2 evidence: allocator caps this kernel at 128 VGPR regardless of launch_bounds/waves_per_eu
// attributes; demanding 192 persistent regs => remat-from-L2 (R1, 6.06us/step) or scratch spill
// (R2+PIN, 9.3us/step). v3 restructures to FIT 128 VGPRs:
//   thread t: cell q=t&127, column-group g=t>>7 (32 cols of the 256 active cols [x;h]).
//   Computes partial i,f,g,o gate sums for cell q over its 32 cols.
//   Weights: gates i,f,g (24 float4 = 96 VGPR) in registers; o-gate row in LDS,
//   column-major [j4][t] => per-step ds_read_b128 is linear (conflict-free, no swizzle).
//   v-broadcast traffic: 128 KB/step (4x less than row-per-thread layout).
__global__ void __launch_bounds__(1024) lstm_kernel(
    const float* __restrict__ inp, const float* __restrict__ embed,
    const float* __restrict__ w_ih, const float* __restrict__ w_hh,
    const float* __restrict__ b_ih, const float* __restrict__ b_hh,
    float* __restrict__ out_cs,                 // d_out[0 .. 64*128)
    unsigned long long* __restrict__ slots)     // ws: 64 argmax slots
{
    __shared__ float4 wlds4[8 * 1024];   // 128 KB: o-gate weights, column-major [j4][t]
    __shared__ float4 part4[8 * 128];    // 16 KB: per-(group, cell) gate partials
    __shared__ float vv[256];            // [x(128) ; h(128)]
    __shared__ float kvlds[512];         // per-row constant: b_ih+b_hh+w_ih[:,128:256].inp

    const int t = threadIdx.x;
    const int q = t & 127;               // cell index
    const int g = t >> 7;                // column group (0..7), wave-uniform (64 | 128)

    if (t < STEPS) slots[t] = 0ull;      // init argmax slots (vocab kernel is stream-ordered after)

    const float4* wih4 = (const float4*)w_ih;   // row stride 64 float4
    const float4* whh4 = (const float4*)w_hh;   // row stride 32 float4

    // Persistent register weights for gates i,f,g (k=0,1,2): rows q+128k, cols [32g,32g+32).
    float4 wr[3][8];
#pragma unroll
    for (int k = 0; k < 3; ++k) {
        const int r = q + 128 * k;
        const float4* src = (g < 4) ? (wih4 + (size_t)r * 64 + g * 8)
                                    : (whh4 + (size_t)r * 32 + (g - 4) * 8);
#pragma unroll
        for (int j4 = 0; j4 < 8; ++j4) wr[k][j4] = src[j4];
    }
    // o-gate (k=3) weights -> LDS column-major
    {
        const int r = q + 384;
        const float4* src = (g < 4) ? (wih4 + (size_t)r * 64 + g * 8)
                                    : (whh4 + (size_t)r * 32 + (g - 4) * 8);
#pragma unroll
        for (int j4 = 0; j4 < 8; ++j4) wlds4[j4 * 1024 + t] = src[j4];
    }

    // kv[r] = b_ih[r] + b_hh[r] + w_ih[r][128:256] . inp  (constant across steps)
    if (t < 512) {
        const float4* wib = wih4 + (size_t)t * 64 + 32;
        const float4* inp4 = (const float4*)inp;
        float k0 = 0.f, k1 = 0.f;
#pragma unroll 4
        for (int j = 0; j < 32; j += 2) {
            k0 += dot4(wib[j], inp4[j]);
            k1 += dot4(wib[j + 1], inp4[j + 1]);
        }
        kvlds[t] = b_ih[t] + b_hh[t] + k0 + k1;
    }

    if (t < 128) { vv[t] = embed[t]; vv[128 + t] = 0.f; }  // x0 = embed[0], h0 = 0
    float creg = 0.f;
    __syncthreads();

    const float4* vv4 = (const float4*)vv;
    const int vb = g * 8;
    for (int step = 0; step < STEPS; ++step) {
        float ax = 0.f, ay = 0.f, az = 0.f, aw = 0.f;
#pragma unroll
        for (int j4 = 0; j4 < 8; ++j4) {
            float4 v  = vv4[vb + j4];               // broadcast (wave-uniform addr)
            float4 w3 = wlds4[j4 * 1024 + t];       // linear per-lane, conflict-free
            ax += dot4(wr[0][j4], v);
            ay += dot4(wr[1][j4], v);
            az += dot4(wr[2][j4], v);
            aw += dot4(w3, v);
        }
        part4[g * 128 + q] = make_float4(ax, ay, az, aw);
        __syncthreads();
        if (t < 128) {
            float4 s = part4[t];                    // g = 0
#pragma unroll
            for (int g2 = 1; g2 < 8; ++g2) {
                float4 p = part4[g2 * 128 + t];
                s.x += p.x; s.y += p.y; s.z += p.z; s.w += p.w;
            }
            float ig = sigm(s.x + kvlds[t]);
            float fg = sigm(s.y + kvlds[128 + t]);
            float gg = tanhf(s.z + kvlds[256 + t]);
            float og = sigm(s.w + kvlds[384 + t]);
            float cn = fg * creg + ig * gg;
            float hn = og * tanhf(cn);
            creg = cn;
            vv[t] = cn;            // next x = c_new
            vv[128 + t] = hn;      // next h
            out_cs[step * 128 + t] = cn;
        }
        __syncthreads();
    }
}

// ---------------- Kernel B: one pass over embed, 64 dots/row + norm + argmax ----------------
// 256 threads, 256 rows/block (4 tiles of 64). Thread = (tx=tid&15 -> t in {tx,tx+16,tx+32,tx+48},
// ry=tid>>4 -> rows {ry,ry+16,ry+32,ry+48}). ssq computed at staging time (per-(row,j4) partials),
// inner loop is pure acc FMAs: 8 b128 LDS reads + 16 dot4 per j4.
__global__ __launch_bounds__(256)
__attribute__((amdgpu_waves_per_eu(2, 2)))
void vocab_kernel(
    const float* __restrict__ embed,
    const float* __restrict__ cs,               // d_out[0..8192): [64][128] c vectors
    unsigned long long* __restrict__ slots)
{
    __shared__ float4 c_lds[64 * 32];   // 32 KB, swizzled [t][j4 ^ (t&31)]
    __shared__ float4 e_lds[64 * 32];   // 32 KB, swizzled; reused as u64 reduction scratch
    __shared__ float ssq_part[64 * 32]; // 8 KB: per-(row,j4) |e4|^2 partials, written at staging

    const int tid = threadIdx.x;
    const int tx = tid & 15, ry = tid >> 4;

    // stage c matrix once (swizzled)
    const float4* cs4 = (const float4*)cs;
#pragma unroll 2
    for (int k = 0; k < 8; ++k) {
        int f = tid + k * 256;
        int row = f >> 5, j4 = f & 31;
        c_lds[row * 32 + (j4 ^ (row & 31))] = cs4[f];
    }

    unsigned long long running = 0ull;   // tid<64: best key for t = tid
    const long long blockbase = (long long)blockIdx.x * 256;
    const float4* embed4 = (const float4*)embed;

    int Pe[4], Pc[4];
#pragma unroll
    for (int rr = 0; rr < 4; ++rr) { int row = ry + 16 * rr; Pe[rr] = row * 32 + (row & 31); }
#pragma unroll
    for (int tt = 0; tt < 4; ++tt) { int t = tx + 16 * tt; Pc[tt] = t * 32 + (t & 31); }

    for (int tile = 0; tile < 4; ++tile) {
        const long long rowbase = blockbase + tile * 64;
        __syncthreads();   // prev reduction reads done before restaging e_lds / ssq_part
#pragma unroll 2
        for (int k = 0; k < 8; ++k) {
            int f = tid + k * 256;
            int row = f >> 5, j4 = f & 31;
            long long grow = rowbase + row;
            float4 val = make_float4(0.f, 0.f, 0.f, 0.f);
            if (grow < VOCAB) val = embed4[grow * 32 + j4];
            e_lds[row * 32 + (j4 ^ (row & 31))] = val;
            ssq_part[row * 32 + j4] = dot4(val, val);
        }
        __syncthreads();

        float acc[4][4];
#pragma unroll
        for (int rr = 0; rr < 4; ++rr)
#pragma unroll
            for (int tt = 0; tt < 4; ++tt) acc[rr][tt] = 0.f;

#pragma unroll 2
        for (int j4 = 0; j4 < 32; ++j4) {
            float4 c0 = c_lds[Pc[0] ^ j4];
            float4 c1 = c_lds[Pc[1] ^ j4];
            float4 c2 = c_lds[Pc[2] ^ j4];
            float4 c3 = c_lds[Pc[3] ^ j4];
#pragma unroll
            for (int rr = 0; rr < 4; ++rr) {
                float4 e = e_lds[Pe[rr] ^ j4];
                acc[rr][0] += dot4(e, c0);
                acc[rr][1] += dot4(e, c1);
                acc[rr][2] += dot4(e, c2);
                acc[rr][3] += dot4(e, c3);
            }
        }

        // per-row inv-norm from staged partials (broadcast reads, once per tile)
        float inv[4];
        long long grows[4];
#pragma unroll
        for (int rr = 0; rr < 4; ++rr) {
            int row = ry + 16 * rr;
            float s0 = 0.f, s1 = 0.f;
#pragma unroll 4
            for (int j = 0; j < 32; j += 2) {
                s0 += ssq_part[row * 32 + j];
                s1 += ssq_part[row * 32 + j + 1];
            }
            inv[rr] = 1.f / fmaxf(sqrtf(s0 + s1), EPSF);
            grows[rr] = rowbase + row;
        }
        __syncthreads();   // all e_lds reads done; safe to reuse as scratch

        unsigned long long* red = (unsigned long long*)e_lds;  // [tt*256 + tx*16 + ry]
#pragma unroll
        for (int tt = 0; tt < 4; ++tt) {
            unsigned long long k = 0ull;
#pragma unroll
            for (int rr = 0; rr < 4; ++rr) {
                if (grows[rr] < VOCAB) {
                    float q = acc[rr][tt] * inv[rr];
                    unsigned long long key = ((unsigned long long)fmap(q) << 32)
                                           | (unsigned)(0x7FFFFFFF - (int)grows[rr]);
                    k = ullmax(k, key);
                }
            }
            red[tt * 256 + tx * 16 + ry] = k;
        }
        __syncthreads();

        if (tid < 64) {
            int t = tid, ttx = t & 15, ttt = t >> 4;
#pragma unroll
            for (int r2 = 0; r2 < 16; ++r2)
                running = ullmax(running, red[ttt * 256 + ttx * 16 + r2]);
        }
    }

    if (tid < 64) atomicMax(&slots[tid], running);
}

// ---------------- Kernel C: decode argmax slots to float indices ----------------
__global__ void finalize_kernel(const unsigned long long* __restrict__ slots,
                                float* __restrict__ out_dec)
{
    int t = threadIdx.x;
    if (t < STEPS) {
        unsigned idx = 0x7FFFFFFFu - (unsigned)(slots[t] & 0xFFFFFFFFu);
        out_dec[t] = (float)idx;
    }
}

extern "C" void kernel_launch(void* const* d_in, const int* in_sizes, int n_in,
                              void* d_out, int out_size, void* d_ws, size_t ws_size,
                              hipStream_t stream) {
    (void)in_sizes; (void)n_in; (void)out_size; (void)ws_size;
    const float* inp   = (const float*)d_in[0];
    const float* embed = (const float*)d_in[1];
    const float* w_ih  = (const float*)d_in[2];
    const float* w_hh  = (const float*)d_in[3];
    const float* b_ih  = (const float*)d_in[4];
    const float* b_hh  = (const float*)d_in[5];
    float* out = (float*)d_out;
    unsigned long long* slots = (unsigned long long*)d_ws;

    hipLaunchKernelGGL(lstm_kernel, dim3(1), dim3(1024), 0, stream,
                       inp, embed, w_ih, w_hh, b_ih, b_hh, out, slots);
    const int nblocks = (VOCAB + 255) / 256;   // 1954
    hipLaunchKernelGGL(vocab_kernel, dim3(nblocks), dim3(256), 0, stream,
                       embed, out, slots);
    hipLaunchKernelGGL(finalize_kernel, dim3(1), dim3(64), 0, stream,
                       slots, out + STEPS * 128);
}